// Round 11
// baseline (94.669 us; speedup 1.0000x reference)
//
#include <hip/hip_runtime.h>
#include <math.h>

#define NL    4096      // coarse points
#define NH    16384     // fine points
#define NF4   64        // 256 features / 4
#define BLK   1024      // threads (16 waves)
#define NW    16
#define FPB   64        // fine points per block (lane = fine point)
#define NHALF 2048      // candidates per scan block (half of NL)
#define SLICE (NHALF / NW) // 128 candidates per wave
#define TOPM  5         // quantized-key shortlist size per list
#define SENT  0x7fffffff

typedef float v8f __attribute__((ext_vector_type(8)));
typedef float v2f __attribute__((ext_vector_type(2)));

// ---- i32 sorted top-5. Keys = (d2-bits & 0xFFFFF000) | j. i32 order puts
// negative-d2 rounding noise first (harmless; exact rescore follows).
__device__ __forceinline__ int med3i(int a, int b, int c)
{
  int d;
  asm("v_med3_i32 %0, %1, %2, %3" : "=v"(d) : "v"(a), "v"(b), "v"(c));
  return d;
}
__device__ __forceinline__ int mini(int a, int b)
{
  int d;
  asm("v_min_i32 %0, %1, %2" : "=v"(d) : "v"(a), "v"(b));
  return d;
}
__device__ __forceinline__ void ins5(int k, int& b0, int& b1, int& b2,
                                     int& b3, int& b4)
{
  const int n0 = mini(b0, k);
  const int n1 = med3i(k, b0, b1);
  const int n2 = med3i(k, b1, b2);
  const int n3 = med3i(k, b2, b3);
  const int n4 = med3i(k, b3, b4);
  b0 = n0; b1 = n1; b2 = n2; b3 = n3; b4 = n4;
}

// Lexicographic (d, j) insert for the exact fp32 rescore (top-3).
__device__ __forceinline__ void lexins3(float d, int j,
    float& b0, float& b1, float& b2, int& i0, int& i1, int& i2)
{
  bool s2 = (d < b2) || ((d == b2) && (j < i2));
  b2 = s2 ? d : b2;  i2 = s2 ? j : i2;
  bool s1 = (b2 < b1) || ((b2 == b1) && (i2 < i1));
  float tf = b1; int ti = i1;
  b1 = s1 ? b2 : b1;  i1 = s1 ? i2 : i1;
  b2 = s1 ? tf : b2;  i2 = s1 ? ti : i2;
  bool s0 = (b1 < b0) || ((b1 == b0) && (i1 < i0));
  tf = b0; ti = i0;
  b0 = s0 ? b1 : b0;  i0 = s0 ? i1 : i0;
  b1 = s0 ? tf : b1;  i1 = s0 ? ti : i1;
}

// Packed distance, per-component bit-identical to the reference sequence.
__device__ __forceinline__ v2f dist2_pk(v2f lx, v2f ly, v2f lz, v2f ll,
                                        v2f h00, v2f h11, v2f h22, v2f hhh,
                                        v2f m22)
{
  v2f d;
  asm("v_pk_mul_f32 %0, %1, %2\n\t"
      "v_pk_fma_f32 %0, %3, %4, %0\n\t"
      "v_pk_fma_f32 %0, %5, %6, %0\n\t"
      "v_pk_fma_f32 %0, %0, %7, %8\n\t"
      "v_pk_add_f32 %0, %0, %9"
      : "=&v"(d)
      : "v"(h00), "s"(lx), "v"(h11), "s"(ly), "v"(h22), "s"(lz),
        "v"(m22), "v"(hhh), "s"(ll));
  return d;
}

#define LOADCH(X, Y, Z, W, P)                                   \
  asm volatile("s_load_dwordx8 %0, %4, 0x0\n\t"                 \
               "s_load_dwordx8 %1, %4, 0x4000\n\t"              \
               "s_load_dwordx8 %2, %4, 0x8000\n\t"              \
               "s_load_dwordx8 %3, %4, 0xc000"                  \
               : "=&s"(X), "=&s"(Y), "=&s"(Z), "=&s"(W)         \
               : "s"(P))
#define WAITCH(X, Y, Z, W)                                      \
  asm volatile("s_waitcnt lgkmcnt(0)"                           \
               : "+s"(X), "+s"(Y), "+s"(Z), "+s"(W))

// ---------- prologue: SoA pack (x | y | z | ll), exact np rounding ----------
__global__ __launch_bounds__(256)
void prep_soa_kernel(const float* __restrict__ pos_l, float* __restrict__ cand)
{
  const int i = blockIdx.x * 256 + threadIdx.x;   // 0..NL-1
  const float l0 = pos_l[i * 3 + 0];
  const float l1 = pos_l[i * 3 + 1];
  const float l2 = pos_l[i * 3 + 2];
  const float ll = __fadd_rn(__fadd_rn(__fmul_rn(l0, l0), __fmul_rn(l1, l1)),
                             __fmul_rn(l2, l2));
  cand[i]          = l0;
  cand[NL + i]     = l1;
  cand[2 * NL + i] = l2;
  cand[3 * NL + i] = ll;
}

// ---------- scan: 512 blocks (2/CU, 8 waves/SIMD), half-range each ----------
__global__ __launch_bounds__(BLK)
void knn_scan_kernel(const float* __restrict__ pos_h,
                     const float* __restrict__ cand,    // SoA x|y|z|ll
                     int* __restrict__ pkeys)           // [2*NH*TOPM]
{
  __shared__ int pk_[NW * FPB * TOPM];   // 20 KB

  const int tid  = threadIdx.x;
  const int lane = tid & 63;
  const int wv   = __builtin_amdgcn_readfirstlane(tid >> 6);
  const int half = blockIdx.x & 1;
  const int fgrp = blockIdx.x >> 1;
  const int fg   = fgrp * FPB + lane;

  const float h0 = pos_h[fg * 3 + 0];
  const float h1 = pos_h[fg * 3 + 1];
  const float h2 = pos_h[fg * 3 + 2];
  const float hh = __fadd_rn(__fadd_rn(__fmul_rn(h0, h0), __fmul_rn(h1, h1)),
                             __fmul_rn(h2, h2));
  const v2f h00 = { h0, h0 }, h11 = { h1, h1 }, h22 = { h2, h2 };
  const v2f hhh = { hh, hh }, m22 = { -2.0f, -2.0f };

  unsigned int kmaskv;
  asm("v_mov_b32 %0, 0xfffff000" : "=v"(kmaskv));

  int a0 = SENT, a1 = SENT, a2 = SENT, a3 = SENT, a4 = SENT;
  int c0 = SENT, c1 = SENT, c2 = SENT, c3 = SENT, c4 = SENT;

  const int jbase = __builtin_amdgcn_readfirstlane(half * NHALF + wv * SLICE);

#define EVAL8(X, Y, Z, W, JB)                                              \
  do {                                                                     \
    _Pragma("unroll")                                                      \
    for (int pr = 0; pr < 4; ++pr) {                                       \
      const v2f lx = { X[2 * pr], X[2 * pr + 1] };                         \
      const v2f ly = { Y[2 * pr], Y[2 * pr + 1] };                         \
      const v2f lz = { Z[2 * pr], Z[2 * pr + 1] };                         \
      const v2f lw = { W[2 * pr], W[2 * pr + 1] };                         \
      const v2f d  = dist2_pk(lx, ly, lz, lw, h00, h11, h22, hhh, m22);    \
      const int j0 = (JB) + 2 * pr;                                        \
      const int j1 = j0 + 1;                                               \
      int k0, k1;                                                          \
      asm("v_and_or_b32 %0, %1, %2, %3"                                    \
          : "=v"(k0) : "v"(d.x), "v"(kmaskv), "s"(j0));                    \
      asm("v_and_or_b32 %0, %1, %2, %3"                                    \
          : "=v"(k1) : "v"(d.y), "v"(kmaskv), "s"(j1));                    \
      ins5(k0, a0, a1, a2, a3, a4);                                        \
      ins5(k1, c0, c1, c2, c3, c4);                                        \
    }                                                                      \
  } while (0)

  // software-pipelined scan over SLICE candidates (8-cand chunks, dbl-buffer)
  {
    v8f ax_, ay_, az_, aw_, bx_, by_, bz_, bw_;
    LOADCH(ax_, ay_, az_, aw_, cand + jbase);
    for (int t = 0; t < SLICE; t += 16) {
      WAITCH(ax_, ay_, az_, aw_);
      LOADCH(bx_, by_, bz_, bw_, cand + jbase + t + 8);
      EVAL8(ax_, ay_, az_, aw_, jbase + t);
      WAITCH(bx_, by_, bz_, bw_);
      LOADCH(ax_, ay_, az_, aw_, cand + jbase + t + 16); // last iter: dead pref
      EVAL8(bx_, by_, bz_, bw_, jbase + t + 8);
    }
    // CRITICAL: drain the final (dead) prefetch. Without this, ax_..aw_ are
    // dead at definition, the allocator reuses their 32 SGPRs for post-loop
    // values, and the in-flight s_load_dwordx8 returns CLOBBER them (the
    // round-10 failure). The "+s" ties extend liveness to this wait.
    WAITCH(ax_, ay_, az_, aw_);
  }
#undef EVAL8

  // merge odd-set into even-set (value-based, order-independent)
  ins5(c0, a0, a1, a2, a3, a4);
  ins5(c1, a0, a1, a2, a3, a4);
  ins5(c2, a0, a1, a2, a3, a4);
  ins5(c3, a0, a1, a2, a3, a4);
  ins5(c4, a0, a1, a2, a3, a4);

  {
    const int s = (wv * FPB + lane) * TOPM;
    pk_[s + 0] = a0; pk_[s + 1] = a1; pk_[s + 2] = a2;
    pk_[s + 3] = a3; pk_[s + 4] = a4;
  }
  __syncthreads();

  // first 64 threads: merge NW wave-lists, emit this half's top-5 keys
  if (tid < FPB) {
    int m0 = SENT, m1 = SENT, m2 = SENT, m3 = SENT, m4 = SENT;
    for (int w = 0; w < NW; ++w) {
      const int s = (w * FPB + tid) * TOPM;
      #pragma unroll
      for (int q = 0; q < TOPM; ++q)
        ins5(pk_[s + q], m0, m1, m2, m3, m4);
    }
    const int o = (half * NH + fgrp * FPB + tid) * TOPM;
    pkeys[o + 0] = m0; pkeys[o + 1] = m1; pkeys[o + 2] = m2;
    pkeys[o + 3] = m3; pkeys[o + 4] = m4;
  }
}

// ---------- finish: exact rescore of 10 survivors, weights, interp ----------
__global__ __launch_bounds__(BLK)
void knn_finish_kernel(const float* __restrict__ x,
                       const float* __restrict__ pos_l,
                       const float* __restrict__ pos_h,
                       const int* __restrict__ pkeys,
                       float* __restrict__ out)
{
  __shared__ float wn[FPB * 3];
  __shared__ int   sj[FPB * 3];
  const int tid = threadIdx.x;

  if (tid < FPB) {
    const int f = blockIdx.x * FPB + tid;
    const float h0 = pos_h[f * 3 + 0];
    const float h1 = pos_h[f * 3 + 1];
    const float h2 = pos_h[f * 3 + 2];
    const float hh = __fadd_rn(__fadd_rn(__fmul_rn(h0, h0), __fmul_rn(h1, h1)),
                               __fmul_rn(h2, h2));

    // exact expansion-form rescore of both halves' shortlists (disjoint j),
    // lexicographic top-3 — replicates the reference's stable top_k exactly.
    float e0 = INFINITY, e1 = INFINITY, e2 = INFINITY;
    int   i0 = 0x7fffffff, i1 = 0x7fffffff, i2 = 0x7fffffff;
    #pragma unroll
    for (int hset = 0; hset < 2; ++hset) {
      const int o = (hset * NH + f) * TOPM;
      #pragma unroll
      for (int q = 0; q < TOPM; ++q) {
        const int j = pkeys[o + q] & 0xFFF;
        const float lx = pos_l[j * 3 + 0];
        const float ly = pos_l[j * 3 + 1];
        const float lz = pos_l[j * 3 + 2];
        // ll recomputed with the EXACT prep/np sequence — bit-identical
        const float ll = __fadd_rn(__fadd_rn(__fmul_rn(lx, lx),
                                             __fmul_rn(ly, ly)),
                                   __fmul_rn(lz, lz));
        const float dot = __fmaf_rn(h2, lz, __fmaf_rn(h1, ly, __fmul_rn(h0, lx)));
        const float d2  = __fadd_rn(__fsub_rn(hh, __fmul_rn(2.0f, dot)), ll);
        lexins3(d2, j, e0, e1, e2, i0, i1, i2);
      }
    }

    // weights: exact diff-form recompute per reference
    float wk[3];
    int   jk[3] = { i0, i1, i2 };
    #pragma unroll
    for (int k = 0; k < 3; ++k) {
      const int j = jk[k];
      const float dx = __fsub_rn(h0, pos_l[j * 3 + 0]);
      const float dy = __fsub_rn(h1, pos_l[j * 3 + 1]);
      const float dz = __fsub_rn(h2, pos_l[j * 3 + 2]);
      float d2 = __fadd_rn(__fadd_rn(__fmul_rn(dx, dx), __fmul_rn(dy, dy)),
                           __fmul_rn(dz, dz));
      d2 = fmaxf(d2, 1e-16f);
      wk[k] = __frcp_rn(d2);
    }
    const float W  = __fadd_rn(__fadd_rn(wk[0], wk[1]), wk[2]);
    const float rW = __frcp_rn(W);
    #pragma unroll
    for (int k = 0; k < 3; ++k) {
      wn[tid * 3 + k] = wk[k] * rW;
      sj[tid * 3 + k] = jk[k];
    }
  }
  __syncthreads();

  // interpolation: 64 fine x 64 float4 = 4096 tasks, 4 per thread
  const float4* __restrict__ x4   = (const float4*)x;
  float4* __restrict__       out4 = (float4*)out;
  #pragma unroll
  for (int i = 0; i < (FPB * NF4) / BLK; ++i) {
    const int task = tid + i * BLK;
    const int f    = task >> 6;
    const int cc   = task & 63;
    const int j0 = sj[f * 3 + 0], j1 = sj[f * 3 + 1], j2 = sj[f * 3 + 2];
    const float w0 = wn[f * 3 + 0], w1 = wn[f * 3 + 1], w2 = wn[f * 3 + 2];
    const float4 xa = x4[j0 * NF4 + cc];
    const float4 xb = x4[j1 * NF4 + cc];
    const float4 xc = x4[j2 * NF4 + cc];
    float4 r;
    r.x = xa.x * w0 + xb.x * w1 + xc.x * w2;
    r.y = xa.y * w0 + xb.y * w1 + xc.y * w2;
    r.z = xa.z * w0 + xb.z * w1 + xc.z * w2;
    r.w = xa.w * w0 + xb.w * w1 + xc.w * w2;
    out4[(blockIdx.x * FPB + f) * NF4 + cc] = r;
  }
}

extern "C" void kernel_launch(void* const* d_in, const int* in_sizes, int n_in,
                              void* d_out, int out_size, void* d_ws, size_t ws_size,
                              hipStream_t stream)
{
  const float* x     = (const float*)d_in[0];   // [4096, 256]
  const float* pos_l = (const float*)d_in[1];   // [4096, 3]
  const float* pos_h = (const float*)d_in[2];   // [16384, 3]
  float* out   = (float*)d_out;                 // [16384, 256]
  float* cand  = (float*)d_ws;                  // SoA x|y|z|ll, 64 KB
  int*   pkeys = (int*)(cand + 4 * NL);         // [2*NH*TOPM] = 640 KB

  hipLaunchKernelGGL(prep_soa_kernel, dim3(NL / 256), dim3(256), 0, stream,
                     pos_l, cand);
  hipLaunchKernelGGL(knn_scan_kernel, dim3((NH / FPB) * 2), dim3(BLK), 0,
                     stream, pos_h, cand, pkeys);
  hipLaunchKernelGGL(knn_finish_kernel, dim3(NH / FPB), dim3(BLK), 0, stream,
                     x, pos_l, pos_h, pkeys, out);
}